// Round 2
// baseline (5817.341 us; speedup 1.0000x reference)
//
#include <hip/hip_runtime.h>
#include <hip/hip_bf16.h>

// R-GCN layer (all fp32): out = relu([agg0/deg0 | agg1/deg1 | x] @ [W0;W1;Wl] + bias)
// agg_r = scatter-sum of x[src_r] at dst_r, deg clamped to >=1.
// Workspace: agg fp32 [2,N,128] (102.4 MB) + deg fp32 [2,N] (0.8 MB).

#define DFEAT 128

__global__ void zero_ws_kernel(float4* __restrict__ ws, long long n4) {
    long long i = (long long)blockIdx.x * blockDim.x + threadIdx.x;
    if (i < n4) ws[i] = make_float4(0.f, 0.f, 0.f, 0.f);
}

// One edge per 32 lanes; edges [0,E) = relation 0, [E,2E) = relation 1.
// Each lane handles 4 features (float4 gather -> 4 fp32 atomics).
__global__ void scatter_edges_kernel(const float* __restrict__ x,
                                     const int* __restrict__ src0,
                                     const int* __restrict__ dst0,
                                     const int* __restrict__ src1,
                                     const int* __restrict__ dst1,
                                     float* __restrict__ agg,
                                     float* __restrict__ degr,
                                     int N, int E) {
    long long gid = (long long)blockIdx.x * blockDim.x + threadIdx.x;
    int edge = (int)(gid >> 5);
    if (edge >= 2 * E) return;
    int lane = (int)(gid & 31);
    int r = (edge >= E) ? 1 : 0;
    int e = edge - r * E;
    int s = r ? src1[e] : src0[e];
    int t = r ? dst1[e] : dst0[e];

    float4 v = ((const float4*)(x + (long long)s * DFEAT))[lane];
    float* arow = agg + ((long long)r * N + t) * DFEAT + 4 * lane;
    atomicAdd(arow + 0, v.x);
    atomicAdd(arow + 1, v.y);
    atomicAdd(arow + 2, v.z);
    atomicAdd(arow + 3, v.w);
    if (lane == 0) atomicAdd(&degr[(long long)r * N + t], 1.0f);
}

// Fused GEMM: C[node, col] over K=384 (agg0/deg0 | agg1/deg1 | x), bias+relu.
// Block: 256 threads, 32 nodes x 128 cols. Thread: 4 nodes x 4 cols.
__global__ __launch_bounds__(256) void fused_gemm_kernel(
        const float* __restrict__ agg, const float* __restrict__ degr,
        const float* __restrict__ x,
        const float* __restrict__ wrel,   // [2,128,128] flat = [k<256][col]
        const float* __restrict__ wloop,  // [128,128]
        const float* __restrict__ bias,   // [128]
        float* __restrict__ out, int N) {
    __shared__ float Ash[32][33];    // [kk][node], +1 pad
    __shared__ float Bsh[32][132];   // [kk][col],  +4 pad (keeps 16B align)
    __shared__ float invd[2][32];

    int tid = threadIdx.x;
    int nb = blockIdx.x * 32;

    if (tid < 64) {
        int r = tid >> 5, i = tid & 31;
        int node = nb + i;
        float dg = (node < N) ? degr[(long long)r * N + node] : 1.0f;
        invd[r][i] = 1.0f / fmaxf(dg, 1.0f);
    }
    __syncthreads();

    int colg = tid & 31;   // cols colg*4 .. colg*4+3
    int nrow = tid >> 5;   // nodes nrow + 8*i, i in [0,4)

    float acc[4][4];
#pragma unroll
    for (int i = 0; i < 4; ++i)
#pragma unroll
        for (int j = 0; j < 4; ++j) acc[i][j] = 0.f;

    for (int kc = 0; kc < 12; ++kc) {
        int k0 = kc * 32;
        // Stage A chunk: 32 k x 32 nodes. Lanes sweep k within a node's row
        // (coalesced 128B per 32 lanes); LDS write stride 33 -> conflict-free.
#pragma unroll
        for (int i = 0; i < 4; ++i) {
            int lin = tid + 256 * i;
            int node = lin >> 5;
            int kk = lin & 31;
            int k = k0 + kk;
            int gnode = nb + node;
            float val = 0.f;
            if (gnode < N) {
                if (k < 256) {
                    int r = k >> 7;
                    int kloc = k & 127;
                    val = agg[((long long)r * N + gnode) * DFEAT + kloc] * invd[r][node];
                } else {
                    val = x[(long long)gnode * DFEAT + (k - 256)];
                }
            }
            Ash[kk][node] = val;
        }
        // Stage B chunk: 32 k x 128 cols.
#pragma unroll
        for (int i = 0; i < 16; ++i) {
            int lin = tid + 256 * i;
            int kk = lin >> 7;
            int col = lin & 127;
            int k = k0 + kk;
            float val;
            if (k < 256) val = wrel[k * DFEAT + col];
            else         val = wloop[(k - 256) * DFEAT + col];
            Bsh[kk][col] = val;
        }
        __syncthreads();

#pragma unroll
        for (int kk = 0; kk < 32; ++kk) {
            float4 b = *(const float4*)&Bsh[kk][colg * 4];
            float a0 = Ash[kk][nrow];
            float a1 = Ash[kk][nrow + 8];
            float a2 = Ash[kk][nrow + 16];
            float a3 = Ash[kk][nrow + 24];
            acc[0][0] += a0 * b.x; acc[0][1] += a0 * b.y; acc[0][2] += a0 * b.z; acc[0][3] += a0 * b.w;
            acc[1][0] += a1 * b.x; acc[1][1] += a1 * b.y; acc[1][2] += a1 * b.z; acc[1][3] += a1 * b.w;
            acc[2][0] += a2 * b.x; acc[2][1] += a2 * b.y; acc[2][2] += a2 * b.z; acc[2][3] += a2 * b.w;
            acc[3][0] += a3 * b.x; acc[3][1] += a3 * b.y; acc[3][2] += a3 * b.z; acc[3][3] += a3 * b.w;
        }
        __syncthreads();
    }

    float bv[4];
#pragma unroll
    for (int j = 0; j < 4; ++j) bv[j] = bias[colg * 4 + j];

#pragma unroll
    for (int i = 0; i < 4; ++i) {
        int gnode = nb + nrow + 8 * i;
        if (gnode < N) {
#pragma unroll
            for (int j = 0; j < 4; ++j) {
                float h = acc[i][j] + bv[j];
                out[(long long)gnode * DFEAT + colg * 4 + j] = fmaxf(h, 0.f);
            }
        }
    }
}

extern "C" void kernel_launch(void* const* d_in, const int* in_sizes, int n_in,
                              void* d_out, int out_size, void* d_ws, size_t ws_size,
                              hipStream_t stream) {
    const float* x      = (const float*)d_in[0];
    const int* src_fwd  = (const int*)d_in[1];
    const int* dst_fwd  = (const int*)d_in[2];
    const int* src_bwd  = (const int*)d_in[3];
    const int* dst_bwd  = (const int*)d_in[4];
    const float* wrel   = (const float*)d_in[5];
    const float* wloop  = (const float*)d_in[6];
    const float* hbias  = (const float*)d_in[7];
    float* out          = (float*)d_out;

    int N = in_sizes[0] / DFEAT;
    int E = in_sizes[1];

    float* agg  = (float*)d_ws;                      // [2, N, 128] fp32
    float* degr = agg + (size_t)2 * N * DFEAT;       // [2, N] fp32
    // needs ws_size >= (2*N*128 + 2*N)*4 = ~103.2 MB

    long long zfloats = (long long)2 * N * DFEAT + 2LL * N;
    long long z4 = zfloats / 4;   // both terms divisible by 4
    int zblocks = (int)((z4 + 255) / 256);
    zero_ws_kernel<<<zblocks, 256, 0, stream>>>((float4*)d_ws, z4);

    long long sthreads = (long long)2 * E * 32;
    int sblocks = (int)((sthreads + 255) / 256);
    scatter_edges_kernel<<<sblocks, 256, 0, stream>>>(
        x, src_fwd, dst_fwd, src_bwd, dst_bwd, agg, degr, N, E);

    int gblocks = (N + 31) / 32;
    fused_gemm_kernel<<<gblocks, 256, 0, stream>>>(
        agg, degr, x, wrel, wloop, hbias, out, N);
}

// Round 3
// 898.476 us; speedup vs baseline: 6.4747x; 6.4747x over previous
//
#include <hip/hip_runtime.h>
#include <hip/hip_bf16.h>

// R-GCN layer (fp32 in/out): out = relu(agg0/deg0 @ W0 + agg1/deg1 @ W1 + x @ Wl + b)
// Round 3: replace 410M fp32 feature atomics (6.5 GB of memory-side RMW writes,
// 5.5 ms) with CSR build (int atomics only) + register accumulation per (r,dst),
// agg stored normalized in bf16.
//
// ws layout (ints): counts[2N] | row_start[2N] | cursor[2N] | bsum[256] |
//                   csr_src[2E] | agg_bf16[2N*128] (as ushort)

#define DFEAT 128

__global__ void zero_counts_kernel(int* __restrict__ c, int n) {
    int i = blockIdx.x * blockDim.x + threadIdx.x;
    if (i < n) c[i] = 0;
}

// histogram of (r,dst)
__global__ void hist_kernel(const int* __restrict__ dst0,
                            const int* __restrict__ dst1,
                            int* __restrict__ counts, int N, int E) {
    int i = blockIdx.x * blockDim.x + threadIdx.x;
    if (i >= 2 * E) return;
    int r = (i >= E) ? 1 : 0;
    int e = i - r * E;
    int t = r ? dst1[e] : dst0[e];
    atomicAdd(&counts[r * N + t], 1);
}

// per-1024-chunk totals
__global__ __launch_bounds__(256) void scan_phase1(const int* __restrict__ counts,
                                                   int* __restrict__ bsum, int M) {
    __shared__ int sh[256];
    int t = threadIdx.x, base = blockIdx.x * 1024;
    int s = 0;
#pragma unroll
    for (int j = 0; j < 4; ++j) {
        int idx = base + t * 4 + j;
        if (idx < M) s += counts[idx];
    }
    sh[t] = s; __syncthreads();
    for (int off = 128; off > 0; off >>= 1) {
        if (t < off) sh[t] += sh[t + off];
        __syncthreads();
    }
    if (t == 0) bsum[blockIdx.x] = sh[0];
}

// exclusive scan of block sums (nb <= 256), single block
__global__ __launch_bounds__(256) void scan_phase2(int* __restrict__ bsum, int nb) {
    __shared__ int sh[256];
    int t = threadIdx.x;
    int v = (t < nb) ? bsum[t] : 0;
    sh[t] = v; __syncthreads();
    for (int off = 1; off < 256; off <<= 1) {
        int add = (t >= off) ? sh[t - off] : 0;
        __syncthreads();
        sh[t] += add;
        __syncthreads();
    }
    if (t < nb) bsum[t] = sh[t] - v;   // exclusive
}

// block-local exclusive scan + block offset -> row_start & cursor
__global__ __launch_bounds__(256) void scan_phase3(const int* __restrict__ counts,
                                                   const int* __restrict__ bsum,
                                                   int* __restrict__ row_start,
                                                   int* __restrict__ cursor, int M) {
    __shared__ int sh[256];
    int t = threadIdx.x, base = blockIdx.x * 1024;
    int v[4]; int s = 0;
#pragma unroll
    for (int j = 0; j < 4; ++j) {
        int idx = base + t * 4 + j;
        v[j] = (idx < M) ? counts[idx] : 0;
        s += v[j];
    }
    sh[t] = s; __syncthreads();
    for (int off = 1; off < 256; off <<= 1) {
        int add = (t >= off) ? sh[t - off] : 0;
        __syncthreads();
        sh[t] += add;
        __syncthreads();
    }
    int run = bsum[blockIdx.x] + sh[t] - s;   // exclusive within grid
#pragma unroll
    for (int j = 0; j < 4; ++j) {
        int idx = base + t * 4 + j;
        if (idx < M) { row_start[idx] = run; cursor[idx] = run; run += v[j]; }
    }
}

// scatter edge src ids into CSR slots (int atomics on cursors)
__global__ void fill_kernel(const int* __restrict__ src0, const int* __restrict__ dst0,
                            const int* __restrict__ src1, const int* __restrict__ dst1,
                            int* __restrict__ cursor, int* __restrict__ csr_src,
                            int N, int E) {
    int i = blockIdx.x * blockDim.x + threadIdx.x;
    if (i >= 2 * E) return;
    int r = (i >= E) ? 1 : 0;
    int e = i - r * E;
    int s = r ? src1[e] : src0[e];
    int t = r ? dst1[e] : dst0[e];
    int slot = atomicAdd(&cursor[r * N + t], 1);
    csr_src[slot] = s;
}

// One half-wave (32 lanes) per (r,node): register-accumulate in-edges,
// normalize by clamped degree, store bf16 row. float4 gathers of x rows.
__global__ __launch_bounds__(256) void agg_gather_kernel(
        const float* __restrict__ x,
        const int* __restrict__ csr_src,
        const int* __restrict__ row_start,
        const int* __restrict__ counts,
        unsigned short* __restrict__ aggb, int M /* = 2N */) {
    int p = blockIdx.x * 8 + (threadIdx.x >> 5);
    if (p >= M) return;
    int lane = threadIdx.x & 31;
    int start = row_start[p];
    int cnt = counts[p];
    const int* eb = csr_src + start;

    float4 acc = make_float4(0.f, 0.f, 0.f, 0.f);
    int e = 0;
    for (; e + 4 <= cnt; e += 4) {
        int s0 = eb[e], s1 = eb[e + 1], s2 = eb[e + 2], s3 = eb[e + 3];
        float4 v0 = ((const float4*)(x + (long long)s0 * DFEAT))[lane];
        float4 v1 = ((const float4*)(x + (long long)s1 * DFEAT))[lane];
        float4 v2 = ((const float4*)(x + (long long)s2 * DFEAT))[lane];
        float4 v3 = ((const float4*)(x + (long long)s3 * DFEAT))[lane];
        acc.x += v0.x + v1.x + v2.x + v3.x;
        acc.y += v0.y + v1.y + v2.y + v3.y;
        acc.z += v0.z + v1.z + v2.z + v3.z;
        acc.w += v0.w + v1.w + v2.w + v3.w;
    }
    for (; e < cnt; ++e) {
        float4 v = ((const float4*)(x + (long long)eb[e] * DFEAT))[lane];
        acc.x += v.x; acc.y += v.y; acc.z += v.z; acc.w += v.w;
    }
    float inv = 1.0f / (float)max(cnt, 1);
    acc.x *= inv; acc.y *= inv; acc.z *= inv; acc.w *= inv;

    ushort4 o;
    o.x = __hip_bfloat16_raw(__float2bfloat16(acc.x)).x;
    o.y = __hip_bfloat16_raw(__float2bfloat16(acc.y)).x;
    o.z = __hip_bfloat16_raw(__float2bfloat16(acc.z)).x;
    o.w = __hip_bfloat16_raw(__float2bfloat16(acc.w)).x;
    *(ushort4*)(aggb + (long long)p * DFEAT + 4 * lane) = o;
}

// Fused GEMM: C[node,col] over K=384 (agg bf16 [2N][128] | x fp32), bias+relu.
// Block: 256 threads, 32 nodes x 128 cols. Thread: 4 nodes x 4 cols.
__global__ __launch_bounds__(256) void fused_gemm_kernel(
        const unsigned short* __restrict__ aggb,
        const float* __restrict__ x,
        const float* __restrict__ wrel,   // [2,128,128] flat = [k<256][col]
        const float* __restrict__ wloop,  // [128,128]
        const float* __restrict__ bias,   // [128]
        float* __restrict__ out, int N) {
    __shared__ float Ash[32][33];    // [kk][node], +1 pad
    __shared__ float Bsh[32][132];   // [kk][col],  +4 pad

    int tid = threadIdx.x;
    int nb = blockIdx.x * 32;

    int colg = tid & 31;   // cols colg*4 .. colg*4+3
    int nrow = tid >> 5;   // nodes nrow + 8*i, i in [0,4)

    float acc[4][4];
#pragma unroll
    for (int i = 0; i < 4; ++i)
#pragma unroll
        for (int j = 0; j < 4; ++j) acc[i][j] = 0.f;

    for (int kc = 0; kc < 12; ++kc) {
        int k0 = kc * 32;
#pragma unroll
        for (int i = 0; i < 4; ++i) {
            int lin = tid + 256 * i;
            int node = lin >> 5;
            int kk = lin & 31;
            int k = k0 + kk;
            int gnode = nb + node;
            float val = 0.f;
            if (gnode < N) {
                if (k < 256) {
                    int r = k >> 7;
                    int kloc = k & 127;
                    __hip_bfloat16_raw hr;
                    hr.x = aggb[((long long)r * N + gnode) * DFEAT + kloc];
                    val = __bfloat162float(__hip_bfloat16(hr));
                } else {
                    val = x[(long long)gnode * DFEAT + (k - 256)];
                }
            }
            Ash[kk][node] = val;
        }
#pragma unroll
        for (int i = 0; i < 16; ++i) {
            int lin = tid + 256 * i;
            int kk = lin >> 7;
            int col = lin & 127;
            int k = k0 + kk;
            float val;
            if (k < 256) val = wrel[k * DFEAT + col];
            else         val = wloop[(k - 256) * DFEAT + col];
            Bsh[kk][col] = val;
        }
        __syncthreads();

#pragma unroll
        for (int kk = 0; kk < 32; ++kk) {
            float4 b = *(const float4*)&Bsh[kk][colg * 4];
            float a0 = Ash[kk][nrow];
            float a1 = Ash[kk][nrow + 8];
            float a2 = Ash[kk][nrow + 16];
            float a3 = Ash[kk][nrow + 24];
            acc[0][0] += a0 * b.x; acc[0][1] += a0 * b.y; acc[0][2] += a0 * b.z; acc[0][3] += a0 * b.w;
            acc[1][0] += a1 * b.x; acc[1][1] += a1 * b.y; acc[1][2] += a1 * b.z; acc[1][3] += a1 * b.w;
            acc[2][0] += a2 * b.x; acc[2][1] += a2 * b.y; acc[2][2] += a2 * b.z; acc[2][3] += a2 * b.w;
            acc[3][0] += a3 * b.x; acc[3][1] += a3 * b.y; acc[3][2] += a3 * b.z; acc[3][3] += a3 * b.w;
        }
        __syncthreads();
    }

    float bv[4];
#pragma unroll
    for (int j = 0; j < 4; ++j) bv[j] = bias[colg * 4 + j];

#pragma unroll
    for (int i = 0; i < 4; ++i) {
        int gnode = nb + nrow + 8 * i;
        if (gnode < N) {
#pragma unroll
            for (int j = 0; j < 4; ++j) {
                float h = acc[i][j] + bv[j];
                out[(long long)gnode * DFEAT + colg * 4 + j] = fmaxf(h, 0.f);
            }
        }
    }
}

extern "C" void kernel_launch(void* const* d_in, const int* in_sizes, int n_in,
                              void* d_out, int out_size, void* d_ws, size_t ws_size,
                              hipStream_t stream) {
    const float* x      = (const float*)d_in[0];
    const int* src_fwd  = (const int*)d_in[1];
    const int* dst_fwd  = (const int*)d_in[2];
    const int* src_bwd  = (const int*)d_in[3];
    const int* dst_bwd  = (const int*)d_in[4];
    const float* wrel   = (const float*)d_in[5];
    const float* wloop  = (const float*)d_in[6];
    const float* hbias  = (const float*)d_in[7];
    float* out          = (float*)d_out;

    int N = in_sizes[0] / DFEAT;
    int E = in_sizes[1];
    int M = 2 * N;               // (r,node) pairs
    int TE = 2 * E;              // total edges

    int* wsI       = (int*)d_ws;
    int* counts    = wsI;                 // [2N]
    int* row_start = wsI + M;             // [2N]
    int* cursor    = wsI + 2 * M;         // [2N]
    int* bsum      = wsI + 3 * M;         // [256]
    int* csr_src   = wsI + 3 * M + 256;   // [2E]
    unsigned short* aggb = (unsigned short*)(csr_src + TE);   // [2N*128] bf16
    // total: (3*2N + 256 + 2E)*4 + 2N*128*2 bytes ~= 66.4 MB

    zero_counts_kernel<<<(M + 255) / 256, 256, 0, stream>>>(counts, M);

    hist_kernel<<<(TE + 255) / 256, 256, 0, stream>>>(dst_fwd, dst_bwd, counts, N, E);

    int nb = (M + 1023) / 1024;   // 196 for N=100k (must be <= 256)
    scan_phase1<<<nb, 256, 0, stream>>>(counts, bsum, M);
    scan_phase2<<<1, 256, 0, stream>>>(bsum, nb);
    scan_phase3<<<nb, 256, 0, stream>>>(counts, bsum, row_start, cursor, M);

    fill_kernel<<<(TE + 255) / 256, 256, 0, stream>>>(
        src_fwd, dst_fwd, src_bwd, dst_bwd, cursor, csr_src, N, E);

    agg_gather_kernel<<<(M + 7) / 8, 256, 0, stream>>>(
        x, csr_src, row_start, counts, aggb, M);

    fused_gemm_kernel<<<(N + 31) / 32, 256, 0, stream>>>(
        aggb, x, wrel, wloop, hbias, out, N);
}